// Round 3
// baseline (725.618 us; speedup 1.0000x reference)
//
#include <hip/hip_runtime.h>
#include <hip/hip_bf16.h>
#include <math.h>

#define NFEAT 512
#define SCAN_BS 256

// ============================================================================
// Phase A: h1p = x @ W1  ([N,512] @ [512,8]) — wave-per-node GEMV.
// Lane owns features [lane*8, lane*8+8); W1 fragment in 64 VGPRs preloaded
// once (~12 nodes/wave amortization at 2048 blocks). Row read fully coalesced
// (64 lanes x 32B = 2KB). This kernel is the HBM floor: 204.8MB of x.
// ============================================================================
__global__ __launch_bounds__(256) void gcn_mm512x8(
    const float* __restrict__ x, const float* __restrict__ W,
    float* __restrict__ out, int N)
{
  const int lane   = threadIdx.x & 63;
  const int wid    = blockIdx.x * (blockDim.x >> 6) + (threadIdx.x >> 6);
  const int nwaves = gridDim.x * (blockDim.x >> 6);

  float Wr[8][8];
  #pragma unroll
  for (int k = 0; k < 8; ++k) {
    const float4 wa = *reinterpret_cast<const float4*>(W + (size_t)(lane*8 + k)*8);
    const float4 wb = *reinterpret_cast<const float4*>(W + (size_t)(lane*8 + k)*8 + 4);
    Wr[k][0]=wa.x; Wr[k][1]=wa.y; Wr[k][2]=wa.z; Wr[k][3]=wa.w;
    Wr[k][4]=wb.x; Wr[k][5]=wb.y; Wr[k][6]=wb.z; Wr[k][7]=wb.w;
  }

  for (int n = wid; n < N; n += nwaves) {
    const float* xr = x + (size_t)n * NFEAT + lane*8;
    const float4 a0 = *reinterpret_cast<const float4*>(xr);
    const float4 a1 = *reinterpret_cast<const float4*>(xr + 4);
    const float a[8] = {a0.x,a0.y,a0.z,a0.w,a1.x,a1.y,a1.z,a1.w};
    float acc[8] = {0.f,0.f,0.f,0.f,0.f,0.f,0.f,0.f};
    #pragma unroll
    for (int k = 0; k < 8; ++k)
      #pragma unroll
      for (int o = 0; o < 8; ++o)
        acc[o] = fmaf(a[k], Wr[k][o], acc[o]);
    #pragma unroll
    for (int o = 0; o < 8; ++o) {
      float v = acc[o];
      v += __shfl_xor(v, 32, 64); v += __shfl_xor(v, 16, 64);
      v += __shfl_xor(v,  8, 64); v += __shfl_xor(v,  4, 64);
      v += __shfl_xor(v,  2, 64); v += __shfl_xor(v,  1, 64);
      acc[o] = v;
    }
    if (lane == 0) {
      float4* op = reinterpret_cast<float4*>(out + (size_t)n*8);
      op[0] = make_float4(acc[0],acc[1],acc[2],acc[3]);
      op[1] = make_float4(acc[4],acc[5],acc[6],acc[7]);
    }
  }
}

// ============================================================================
// Phase B: CSR build (dst-indexed), built once, reused by all 4 layers.
// Packed payload: int2{src, float_bits(w)} -> one 8B load per edge later.
// ============================================================================
__global__ __launch_bounds__(256) void gcn_hist(
    const int* __restrict__ dst, int* __restrict__ deg, int E)
{
  const int e = blockIdx.x * blockDim.x + threadIdx.x;
  if (e < E) atomicAdd(&deg[dst[e]], 1);
}

// block-level exclusive scan (Hillis-Steele in LDS); emits per-block totals
__global__ __launch_bounds__(SCAN_BS) void gcn_scan_block(
    const int* __restrict__ deg, int* __restrict__ exc,
    int* __restrict__ bsums, int N)
{
  __shared__ int sm[SCAN_BS];
  const int i = blockIdx.x * SCAN_BS + threadIdx.x;
  const int v = (i < N) ? deg[i] : 0;
  sm[threadIdx.x] = v;
  __syncthreads();
  for (int off = 1; off < SCAN_BS; off <<= 1) {
    const int t = (threadIdx.x >= off) ? sm[threadIdx.x - off] : 0;
    __syncthreads();
    sm[threadIdx.x] += t;
    __syncthreads();
  }
  if (i < N) exc[i] = sm[threadIdx.x] - v;                 // exclusive-in-block
  if (threadIdx.x == SCAN_BS-1) bsums[blockIdx.x] = sm[threadIdx.x];
}

// single-block exclusive scan of the block sums (NB <= 1024; here NB=391)
__global__ __launch_bounds__(1024) void gcn_scan_bsums(int* __restrict__ bsums, int NB)
{
  __shared__ int sm[1024];
  const int t = threadIdx.x;
  const int v = (t < NB) ? bsums[t] : 0;
  sm[t] = v;
  __syncthreads();
  for (int off = 1; off < 1024; off <<= 1) {
    const int u = (t >= off) ? sm[t - off] : 0;
    __syncthreads();
    sm[t] += u;
    __syncthreads();
  }
  if (t < NB) bsums[t] = sm[t] - v;                        // exclusive
}

__global__ __launch_bounds__(SCAN_BS) void gcn_scan_add(
    int* __restrict__ exc, const int* __restrict__ bsums, int N)
{
  const int i = blockIdx.x * SCAN_BS + threadIdx.x;
  if (i < N) exc[i] += bsums[blockIdx.x];
}

// permute edges into CSR slots; one scattered 8B write per edge (L2-absorbed:
// the 25.6MB csr array fits in aggregate L2)
__global__ __launch_bounds__(256) void gcn_csr_scatter(
    const int* __restrict__ src, const int* __restrict__ dst,
    const float* __restrict__ w, const int* __restrict__ rowoff,
    int* __restrict__ cur, int2* __restrict__ csr, int E)
{
  const int e = blockIdx.x * blockDim.x + threadIdx.x;
  if (e >= E) return;
  const int d = dst[e];
  const int pos = rowoff[d] + atomicAdd(&cur[d], 1);
  csr[pos] = make_int2(src[e], __float_as_int(w[e]));
}

// ============================================================================
// Phase C: fused layer — 16 lanes per node (avg degree 32 -> ~2 edges/lane).
// Lanes stride the node's CSR segment; gathers of hin rows hit L2/LLC
// (tables are 3.2-6.4MB). 4-round xor-reduce within the 16-lane group leaves
// the full agg vector in every lane; sublane o<FOUT emits one output column
// of relu(agg+b) @ W.
// ============================================================================
template<int FIN, int FOUT>
__global__ __launch_bounds__(256) void gcn_agg_layer(
    const int* __restrict__ rowoff, const int2* __restrict__ csr,
    const float* __restrict__ hin,
    const float* __restrict__ bias, const float* __restrict__ W,
    float* __restrict__ hout, int N, int E)
{
  const int sub = threadIdx.x & 15;
  const int n   = (blockIdx.x * blockDim.x + threadIdx.x) >> 4;
  if (n >= N) return;
  const int beg = rowoff[n];
  const int end = (n + 1 < N) ? rowoff[n + 1] : E;

  float acc[FIN];
  #pragma unroll
  for (int k = 0; k < FIN; ++k) acc[k] = 0.f;

  for (int e = beg + sub; e < end; e += 16) {
    const int2  sw = csr[e];
    const float wt = __int_as_float(sw.y);
    const float* hp = hin + (size_t)sw.x * FIN;
    if constexpr ((FIN & 3) == 0) {
      #pragma unroll
      for (int q = 0; q < FIN/4; ++q) {
        const float4 v = reinterpret_cast<const float4*>(hp)[q];
        acc[q*4+0] = fmaf(v.x, wt, acc[q*4+0]);
        acc[q*4+1] = fmaf(v.y, wt, acc[q*4+1]);
        acc[q*4+2] = fmaf(v.z, wt, acc[q*4+2]);
        acc[q*4+3] = fmaf(v.w, wt, acc[q*4+3]);
      }
    } else {
      #pragma unroll
      for (int q = 0; q < FIN/2; ++q) {
        const float2 v = reinterpret_cast<const float2*>(hp)[q];
        acc[q*2+0] = fmaf(v.x, wt, acc[q*2+0]);
        acc[q*2+1] = fmaf(v.y, wt, acc[q*2+1]);
      }
    }
  }
  // reduce across the 16-lane group (xor masks stay inside the group)
  #pragma unroll
  for (int k = 0; k < FIN; ++k) {
    float v = acc[k];
    v += __shfl_xor(v, 8, 64); v += __shfl_xor(v, 4, 64);
    v += __shfl_xor(v, 2, 64); v += __shfl_xor(v, 1, 64);
    acc[k] = v;                                  // every lane has the sum
  }
  #pragma unroll
  for (int k = 0; k < FIN; ++k) {
    const float t = acc[k] + bias[k];
    acc[k] = t > 0.f ? t : 0.f;
  }
  if (sub < FOUT) {
    float o = 0.f;
    #pragma unroll
    for (int k = 0; k < FIN; ++k)
      o = fmaf(acc[k], W[k*FOUT + sub], o);
    hout[(size_t)n*FOUT + sub] = o;
  }
}

// final layer: agg(FIN=10) + b4, then log_softmax, straight to d_out
__global__ __launch_bounds__(256) void gcn_agg_final(
    const int* __restrict__ rowoff, const int2* __restrict__ csr,
    const float* __restrict__ hin,
    const float* __restrict__ bias, float* __restrict__ out, int N, int E)
{
  const int sub = threadIdx.x & 15;
  const int n   = (blockIdx.x * blockDim.x + threadIdx.x) >> 4;
  if (n >= N) return;
  const int beg = rowoff[n];
  const int end = (n + 1 < N) ? rowoff[n + 1] : E;

  float acc[10];
  #pragma unroll
  for (int k = 0; k < 10; ++k) acc[k] = 0.f;

  for (int e = beg + sub; e < end; e += 16) {
    const int2  sw = csr[e];
    const float wt = __int_as_float(sw.y);
    const float* hp = hin + (size_t)sw.x * 10;   // 40B rows -> 8B aligned
    #pragma unroll
    for (int q = 0; q < 5; ++q) {
      const float2 v = reinterpret_cast<const float2*>(hp)[q];
      acc[q*2+0] = fmaf(v.x, wt, acc[q*2+0]);
      acc[q*2+1] = fmaf(v.y, wt, acc[q*2+1]);
    }
  }
  #pragma unroll
  for (int k = 0; k < 10; ++k) {
    float v = acc[k];
    v += __shfl_xor(v, 8, 64); v += __shfl_xor(v, 4, 64);
    v += __shfl_xor(v, 2, 64); v += __shfl_xor(v, 1, 64);
    acc[k] = v + bias[k];
  }
  float m = acc[0];
  #pragma unroll
  for (int k = 1; k < 10; ++k) m = fmaxf(m, acc[k]);
  float s = 0.f;
  #pragma unroll
  for (int k = 0; k < 10; ++k) s += expf(acc[k] - m);
  const float ls = logf(s) + m;
  if (sub < 10)
    out[(size_t)n*10 + sub] = acc[sub] - ls;
}

// ============================================================================
extern "C" void kernel_launch(void* const* d_in, const int* in_sizes, int n_in,
                              void* d_out, int out_size, void* d_ws, size_t ws_size,
                              hipStream_t stream)
{
  const float* x  = (const float*)d_in[0];
  const int*   ei = (const int*)  d_in[1];
  const float* ew = (const float*)d_in[2];
  const float* W1 = (const float*)d_in[3];
  const float* b1 = (const float*)d_in[4];
  const float* W2 = (const float*)d_in[5];
  const float* b2 = (const float*)d_in[6];
  const float* W3 = (const float*)d_in[7];
  const float* b3 = (const float*)d_in[8];
  const float* W4 = (const float*)d_in[9];
  const float* b4 = (const float*)d_in[10];

  const int N = in_sizes[0] / NFEAT;     // 100000
  const int E = in_sizes[2];             // 3200000
  const int* src = ei;                   // edge_index[0]
  const int* dst = ei + E;               // edge_index[1]

  const int NB = (N + SCAN_BS - 1) / SCAN_BS;   // 391 (<=1024 req'd by bsums scan)

  // ---- workspace carve-up (4B units), ~38.4MB total ----
  int*   wsp    = (int*)d_ws;
  int*   deg    = wsp;                          // N   (reused as scatter cursor)
  int*   rowoff = wsp + N;                      // N   (exclusive prefix of deg)
  int*   bsums  = wsp + 2*(size_t)N;            // 1024
  int2*  csr    = (int2*)(wsp + 2*(size_t)N + 1024);  // E int2 (8B-aligned: offset even)
  float* h8     = (float*)(csr + E);            // N*8   (h1p, later h3p)
  float* h16    = h8 + (size_t)N*8;             // N*16  (h2p; later reused as h4p)
  float* h10    = h16;                          //        h4p aliases dead h16
  float* outp   = (float*)d_out;

  const int eb  = (E + 255) / 256;
  const int nb16 = (N*16 + 255) / 256;          // 16 lanes per node

  // ---- CSR build (once; reused by all 4 propagations) ----
  hipMemsetAsync(deg, 0, (size_t)N*sizeof(int), stream);
  gcn_hist<<<eb, 256, 0, stream>>>(dst, deg, E);
  gcn_scan_block<<<NB, SCAN_BS, 0, stream>>>(deg, rowoff, bsums, N);
  gcn_scan_bsums<<<1, 1024, 0, stream>>>(bsums, NB);
  gcn_scan_add<<<NB, SCAN_BS, 0, stream>>>(rowoff, bsums, N);
  hipMemsetAsync(deg, 0, (size_t)N*sizeof(int), stream);   // reuse as cursor
  gcn_csr_scatter<<<eb, 256, 0, stream>>>(src, dst, ew, rowoff, deg, csr, E);

  // ---- dense first projection (the only big read: 205MB of x) ----
  gcn_mm512x8<<<2048, 256, 0, stream>>>(x, W1, h8, N);

  // ---- four fused propagate+transform layers ----
  gcn_agg_layer<8,16><<<nb16, 256, 0, stream>>>(rowoff, csr, h8,  b1, W2, h16, N, E);
  gcn_agg_layer<16,8><<<nb16, 256, 0, stream>>>(rowoff, csr, h16, b2, W3, h8,  N, E);
  gcn_agg_layer<8,10><<<nb16, 256, 0, stream>>>(rowoff, csr, h8,  b3, W4, h10, N, E);
  gcn_agg_final<<<nb16, 256, 0, stream>>>(rowoff, csr, h10, b4, outp, N, E);
}

// Round 5
// 714.052 us; speedup vs baseline: 1.0162x; 1.0162x over previous
//
#include <hip/hip_runtime.h>
#include <hip/hip_bf16.h>
#include <math.h>

#define NFEAT 512
#define SCAN_BS 256

// ============================================================================
// Phase A: h1p = x @ W1  ([N,512] @ [512,8]) — wave-per-node GEMV.
// Lane owns features [lane*8, lane*8+8); W1 fragment in 64 VGPRs preloaded
// once. Row read fully coalesced (64 lanes x 32B = 2KB). HBM floor: 205MB.
// ============================================================================
__global__ __launch_bounds__(256) void gcn_mm512x8(
    const float* __restrict__ x, const float* __restrict__ W,
    float* __restrict__ out, int N)
{
  const int lane   = threadIdx.x & 63;
  const int wid    = blockIdx.x * (blockDim.x >> 6) + (threadIdx.x >> 6);
  const int nwaves = gridDim.x * (blockDim.x >> 6);

  float Wr[8][8];
  #pragma unroll
  for (int k = 0; k < 8; ++k) {
    const float4 wa = *reinterpret_cast<const float4*>(W + (size_t)(lane*8 + k)*8);
    const float4 wb = *reinterpret_cast<const float4*>(W + (size_t)(lane*8 + k)*8 + 4);
    Wr[k][0]=wa.x; Wr[k][1]=wa.y; Wr[k][2]=wa.z; Wr[k][3]=wa.w;
    Wr[k][4]=wb.x; Wr[k][5]=wb.y; Wr[k][6]=wb.z; Wr[k][7]=wb.w;
  }

  for (int n = wid; n < N; n += nwaves) {
    const float* xr = x + (size_t)n * NFEAT + lane*8;
    const float4 a0 = *reinterpret_cast<const float4*>(xr);
    const float4 a1 = *reinterpret_cast<const float4*>(xr + 4);
    const float a[8] = {a0.x,a0.y,a0.z,a0.w,a1.x,a1.y,a1.z,a1.w};
    float acc[8] = {0.f,0.f,0.f,0.f,0.f,0.f,0.f,0.f};
    #pragma unroll
    for (int k = 0; k < 8; ++k)
      #pragma unroll
      for (int o = 0; o < 8; ++o)
        acc[o] = fmaf(a[k], Wr[k][o], acc[o]);
    #pragma unroll
    for (int o = 0; o < 8; ++o) {
      float v = acc[o];
      v += __shfl_xor(v, 32, 64); v += __shfl_xor(v, 16, 64);
      v += __shfl_xor(v,  8, 64); v += __shfl_xor(v,  4, 64);
      v += __shfl_xor(v,  2, 64); v += __shfl_xor(v,  1, 64);
      acc[o] = v;
    }
    if (lane == 0) {
      float4* op = reinterpret_cast<float4*>(out + (size_t)n*8);
      op[0] = make_float4(acc[0],acc[1],acc[2],acc[3]);
      op[1] = make_float4(acc[4],acc[5],acc[6],acc[7]);
    }
  }
}

// ============================================================================
// Phase B: CSR build. Histogram pass ALSO emits each edge's within-dst rank
// (the atomic's return value) so the permutation pass needs no atomics.
// ============================================================================
__global__ __launch_bounds__(256) void gcn_hist_rank(
    const int* __restrict__ dst, int* __restrict__ deg,
    int* __restrict__ rank, int E)
{
  const int e = blockIdx.x * blockDim.x + threadIdx.x;
  if (e < E) rank[e] = atomicAdd(&deg[dst[e]], 1);   // coalesced rank store
}

// block-level exclusive scan (Hillis-Steele in LDS); emits per-block totals
__global__ __launch_bounds__(SCAN_BS) void gcn_scan_block(
    const int* __restrict__ deg, int* __restrict__ exc,
    int* __restrict__ bsums, int N)
{
  __shared__ int sm[SCAN_BS];
  const int i = blockIdx.x * SCAN_BS + threadIdx.x;
  const int v = (i < N) ? deg[i] : 0;
  sm[threadIdx.x] = v;
  __syncthreads();
  for (int off = 1; off < SCAN_BS; off <<= 1) {
    const int t = (threadIdx.x >= off) ? sm[threadIdx.x - off] : 0;
    __syncthreads();
    sm[threadIdx.x] += t;
    __syncthreads();
  }
  if (i < N) exc[i] = sm[threadIdx.x] - v;                 // exclusive-in-block
  if (threadIdx.x == SCAN_BS-1) bsums[blockIdx.x] = sm[threadIdx.x];
}

// single-block exclusive scan of the block sums (NB <= 1024; here NB=391)
__global__ __launch_bounds__(1024) void gcn_scan_bsums(int* __restrict__ bsums, int NB)
{
  __shared__ int sm[1024];
  const int t = threadIdx.x;
  const int v = (t < NB) ? bsums[t] : 0;
  sm[t] = v;
  __syncthreads();
  for (int off = 1; off < 1024; off <<= 1) {
    const int u = (t >= off) ? sm[t - off] : 0;
    __syncthreads();
    sm[t] += u;
    __syncthreads();
  }
  if (t < NB) bsums[t] = sm[t] - v;                        // exclusive
}

__global__ __launch_bounds__(SCAN_BS) void gcn_scan_add(
    int* __restrict__ exc, const int* __restrict__ bsums, int N)
{
  const int i = blockIdx.x * SCAN_BS + threadIdx.x;
  if (i < N) exc[i] += bsums[blockIdx.x];
}

// permute edges into CSR slots — ATOMIC-FREE: slot = rowoff[dst] + rank.
// All loads coalesced (dst/rank/src/w) or L2-resident (rowoff). The scattered
// 8B store is NONTEMPORAL: random 8B stores through L2 evict dirty partial
// lines (v3 measured 200MB writeback); nt bypasses allocation so partial
// lines go out at sub-line granularity.
__global__ __launch_bounds__(256) void gcn_csr_scatter(
    const int* __restrict__ src, const int* __restrict__ dst,
    const float* __restrict__ w, const int* __restrict__ rowoff,
    const int* __restrict__ rank, int2* __restrict__ csr, int E)
{
  const int e = blockIdx.x * blockDim.x + threadIdx.x;
  if (e >= E) return;
  const int pos = rowoff[dst[e]] + rank[e];
  const unsigned long long payload =
      (unsigned long long)(unsigned)src[e] |
      ((unsigned long long)(unsigned)__float_as_int(w[e]) << 32);
  __builtin_nontemporal_store(payload, (unsigned long long*)&csr[pos]);
}

// ============================================================================
// Phase C: fused layer — 16 lanes per node (avg degree 32 -> ~2 edges/lane).
// Lanes stride the node's CSR segment; gathers of hin rows hit L2/LLC
// (tables are 3.2-6.4MB). 4-round xor-reduce within the 16-lane group leaves
// the full agg vector in every lane; sublane o<FOUT emits one output column
// of relu(agg+b) @ W.
// ============================================================================
template<int FIN, int FOUT>
__global__ __launch_bounds__(256) void gcn_agg_layer(
    const int* __restrict__ rowoff, const int2* __restrict__ csr,
    const float* __restrict__ hin,
    const float* __restrict__ bias, const float* __restrict__ W,
    float* __restrict__ hout, int N, int E)
{
  const int sub = threadIdx.x & 15;
  const int n   = (blockIdx.x * blockDim.x + threadIdx.x) >> 4;
  if (n >= N) return;
  const int beg = rowoff[n];
  const int end = (n + 1 < N) ? rowoff[n + 1] : E;

  float acc[FIN];
  #pragma unroll
  for (int k = 0; k < FIN; ++k) acc[k] = 0.f;

  for (int e = beg + sub; e < end; e += 16) {
    const int2  sw = csr[e];
    const float wt = __int_as_float(sw.y);
    const float* hp = hin + (size_t)sw.x * FIN;
    if constexpr ((FIN & 3) == 0) {
      #pragma unroll
      for (int q = 0; q < FIN/4; ++q) {
        const float4 v = reinterpret_cast<const float4*>(hp)[q];
        acc[q*4+0] = fmaf(v.x, wt, acc[q*4+0]);
        acc[q*4+1] = fmaf(v.y, wt, acc[q*4+1]);
        acc[q*4+2] = fmaf(v.z, wt, acc[q*4+2]);
        acc[q*4+3] = fmaf(v.w, wt, acc[q*4+3]);
      }
    } else {
      #pragma unroll
      for (int q = 0; q < FIN/2; ++q) {
        const float2 v = reinterpret_cast<const float2*>(hp)[q];
        acc[q*2+0] = fmaf(v.x, wt, acc[q*2+0]);
        acc[q*2+1] = fmaf(v.y, wt, acc[q*2+1]);
      }
    }
  }
  // reduce across the 16-lane group (xor masks stay inside the group)
  #pragma unroll
  for (int k = 0; k < FIN; ++k) {
    float v = acc[k];
    v += __shfl_xor(v, 8, 64); v += __shfl_xor(v, 4, 64);
    v += __shfl_xor(v, 2, 64); v += __shfl_xor(v, 1, 64);
    acc[k] = v;                                  // every lane has the sum
  }
  #pragma unroll
  for (int k = 0; k < FIN; ++k) {
    const float t = acc[k] + bias[k];
    acc[k] = t > 0.f ? t : 0.f;
  }
  if (sub < FOUT) {
    float o = 0.f;
    #pragma unroll
    for (int k = 0; k < FIN; ++k)
      o = fmaf(acc[k], W[k*FOUT + sub], o);
    hout[(size_t)n*FOUT + sub] = o;
  }
}

// final layer: agg(FIN=10) + b4, then log_softmax, straight to d_out
__global__ __launch_bounds__(256) void gcn_agg_final(
    const int* __restrict__ rowoff, const int2* __restrict__ csr,
    const float* __restrict__ hin,
    const float* __restrict__ bias, float* __restrict__ out, int N, int E)
{
  const int sub = threadIdx.x & 15;
  const int n   = (blockIdx.x * blockDim.x + threadIdx.x) >> 4;
  if (n >= N) return;
  const int beg = rowoff[n];
  const int end = (n + 1 < N) ? rowoff[n + 1] : E;

  float acc[10];
  #pragma unroll
  for (int k = 0; k < 10; ++k) acc[k] = 0.f;

  for (int e = beg + sub; e < end; e += 16) {
    const int2  sw = csr[e];
    const float wt = __int_as_float(sw.y);
    const float* hp = hin + (size_t)sw.x * 10;   // 40B rows -> 8B aligned
    #pragma unroll
    for (int q = 0; q < 5; ++q) {
      const float2 v = reinterpret_cast<const float2*>(hp)[q];
      acc[q*2+0] = fmaf(v.x, wt, acc[q*2+0]);
      acc[q*2+1] = fmaf(v.y, wt, acc[q*2+1]);
    }
  }
  #pragma unroll
  for (int k = 0; k < 10; ++k) {
    float v = acc[k];
    v += __shfl_xor(v, 8, 64); v += __shfl_xor(v, 4, 64);
    v += __shfl_xor(v, 2, 64); v += __shfl_xor(v, 1, 64);
    acc[k] = v + bias[k];
  }
  float m = acc[0];
  #pragma unroll
  for (int k = 1; k < 10; ++k) m = fmaxf(m, acc[k]);
  float s = 0.f;
  #pragma unroll
  for (int k = 0; k < 10; ++k) s += expf(acc[k] - m);
  const float ls = logf(s) + m;
  if (sub < 10)
    out[(size_t)n*10 + sub] = acc[sub] - ls;
}

// ============================================================================
extern "C" void kernel_launch(void* const* d_in, const int* in_sizes, int n_in,
                              void* d_out, int out_size, void* d_ws, size_t ws_size,
                              hipStream_t stream)
{
  const float* x  = (const float*)d_in[0];
  const int*   ei = (const int*)  d_in[1];
  const float* ew = (const float*)d_in[2];
  const float* W1 = (const float*)d_in[3];
  const float* b1 = (const float*)d_in[4];
  const float* W2 = (const float*)d_in[5];
  const float* b2 = (const float*)d_in[6];
  const float* W3 = (const float*)d_in[7];
  const float* b3 = (const float*)d_in[8];
  const float* W4 = (const float*)d_in[9];
  const float* b4 = (const float*)d_in[10];

  const int N = in_sizes[0] / NFEAT;     // 100000
  const int E = in_sizes[2];             // 3200000
  const int* src = ei;                   // edge_index[0]
  const int* dst = ei + E;               // edge_index[1]

  const int NB = (N + SCAN_BS - 1) / SCAN_BS;   // 391 (<=1024 req'd by bsums scan)

  // ---- workspace carve-up (4B units), ~51MB total ----
  int*   wsp    = (int*)d_ws;
  int*   deg    = wsp;                          // N
  int*   rowoff = wsp + N;                      // N   (exclusive prefix of deg)
  int*   bsums  = wsp + 2*(size_t)N;            // 1024
  int*   rank   = wsp + 2*(size_t)N + 1024;     // E   (within-dst edge rank)
  int2*  csr    = (int2*)(rank + E);            // E int2 (8B-aligned offset)
  float* h8     = (float*)(csr + E);            // N*8   (h1p, later h3p)
  float* h16    = h8 + (size_t)N*8;             // N*16  (h2p; later reused as h4p)
  float* h10    = h16;                          //        h4p aliases dead h16
  float* outp   = (float*)d_out;

  const int eb   = (E + 255) / 256;
  const int nb16 = (N*16 + 255) / 256;          // 16 lanes per node

  // ---- CSR build (once; reused by all 4 propagations) ----
  hipMemsetAsync(deg, 0, (size_t)N*sizeof(int), stream);
  gcn_hist_rank<<<eb, 256, 0, stream>>>(dst, deg, rank, E);
  gcn_scan_block<<<NB, SCAN_BS, 0, stream>>>(deg, rowoff, bsums, N);
  gcn_scan_bsums<<<1, 1024, 0, stream>>>(bsums, NB);
  gcn_scan_add<<<NB, SCAN_BS, 0, stream>>>(rowoff, bsums, N);
  gcn_csr_scatter<<<eb, 256, 0, stream>>>(src, dst, ew, rowoff, rank, csr, E);

  // ---- dense first projection (the only big read: 205MB of x) ----
  gcn_mm512x8<<<2048, 256, 0, stream>>>(x, W1, h8, N);

  // ---- four fused propagate+transform layers ----
  gcn_agg_layer<8,16><<<nb16, 256, 0, stream>>>(rowoff, csr, h8,  b1, W2, h16, N, E);
  gcn_agg_layer<16,8><<<nb16, 256, 0, stream>>>(rowoff, csr, h16, b2, W3, h8,  N, E);
  gcn_agg_layer<8,10><<<nb16, 256, 0, stream>>>(rowoff, csr, h8,  b3, W4, h10, N, E);
  gcn_agg_final<<<nb16, 256, 0, stream>>>(rowoff, csr, h10, b4, outp, N, E);
}